// Round 1
// baseline (805.646 us; speedup 1.0000x reference)
//
#include <hip/hip_runtime.h>
#include <hip/hip_bf16.h>
#include <cstdint>
#include <cmath>

typedef __bf16 bf16;
typedef __bf16 bf16x8 __attribute__((ext_vector_type(8)));
typedef __bf16 bf16x4 __attribute__((ext_vector_type(4)));
typedef float f32x4 __attribute__((ext_vector_type(4)));

#define NROWS 8192
#define UNITS 2048

// ---- async global->LDS, 16B per lane; lds must be the wave-uniform chunk base.
__device__ __forceinline__ void gload_lds16(const bf16* g, bf16* lds) {
  __builtin_amdgcn_global_load_lds(
      (const __attribute__((address_space(1))) uint32_t*)(uintptr_t)g,
      (__attribute__((address_space(3))) uint32_t*)(uint32_t)(uintptr_t)lds,
      16, 0, 0);
}

// ---- pack x,y fp32 -> bf16 (vectorized float4 -> bf16x4)
__global__ void pack_xy_kernel(const float* __restrict__ x, const float* __restrict__ y,
                               bf16* __restrict__ xb, bf16* __restrict__ yb) {
  size_t n4 = (size_t)NROWS * UNITS / 4;
  size_t stride = (size_t)gridDim.x * blockDim.x;
  for (size_t i = (size_t)blockIdx.x * blockDim.x + threadIdx.x; i < n4; i += stride) {
    float4 vx = ((const float4*)x)[i];
    float4 vy = ((const float4*)y)[i];
    bf16x4 ox = {(bf16)vx.x, (bf16)vx.y, (bf16)vx.z, (bf16)vx.w};
    bf16x4 oy = {(bf16)vy.x, (bf16)vy.y, (bf16)vy.z, (bf16)vy.w};
    ((bf16x4*)xb)[i] = ox;
    ((bf16x4*)yb)[i] = oy;
  }
}

// ---- tiled transpose + convert: dst[j*ldd + koff + k] = (bf16) src[k*2048 + j]
__global__ void transpose_cvt_kernel(const float* __restrict__ src, bf16* __restrict__ dst,
                                     int ldd, int koff) {
  __shared__ float t[32][33];
  int j0 = blockIdx.x * 32, k0 = blockIdx.y * 32;
  int tx = threadIdx.x & 31, ty = threadIdx.x >> 5;  // 32x8
#pragma unroll
  for (int i = 0; i < 32; i += 8)
    t[ty + i][tx] = src[(size_t)(k0 + ty + i) * UNITS + j0 + tx];
  __syncthreads();
#pragma unroll
  for (int i = 0; i < 32; i += 8)
    dst[(size_t)(j0 + ty + i) * ldd + koff + k0 + tx] = (bf16)t[tx][ty + i];
}

// ---- 128x128-tile bf16 GEMM, C = A @ Bt^T, fp32 accum. A split into two K-ranges
// (A0 for k<ksplit, A1 for k>=ksplit). Bt is row-major [Ncols][K].
// EPI 0: cols<2048 -> z=acc+ba+bb -> zbuf ; cols>=2048 -> rx=(acc+bc+bd)*x -> rxbuf (bf16)
// EPI 1: out = (1-z)*x + z*tanh(acc+ba+bb)
template <int EPI>
__global__ __launch_bounds__(256)
void gemm_bt(const bf16* __restrict__ A0, const bf16* __restrict__ A1,
             const bf16* __restrict__ Bt,
             int lda0, int lda1, int ldb, int ksplit, int K,
             const float* __restrict__ bias_a, const float* __restrict__ bias_b,
             const float* __restrict__ bias_c, const float* __restrict__ bias_d,
             const float* __restrict__ xin, float* __restrict__ zbuf,
             bf16* __restrict__ rxbuf, float* __restrict__ outbuf) {
  __shared__ bf16 As[128 * 32];
  __shared__ bf16 Bs[128 * 32];
  const int tid = threadIdx.x;
  const int wave = tid >> 6, lane = tid & 63;
  const int wr = wave >> 1, wc = wave & 1;
  const int brow = blockIdx.y * 128;
  const int bcol = blockIdx.x * 128;

  f32x4 acc[4][4];
#pragma unroll
  for (int m = 0; m < 4; ++m)
#pragma unroll
    for (int n = 0; n < 4; ++n) {
      f32x4 zz = {0.f, 0.f, 0.f, 0.f};
      acc[m][n] = zz;
    }

  const int lrow = lane & 15;
  const int kb = (lane >> 4) * 8;
  const int srow = lane >> 2;       // 0..15 within a 16-row chunk
  const int scol = (lane & 3) * 8;  // 0,8,16,24

  for (int k0 = 0; k0 < K; k0 += 32) {
    const bf16* Abase;
    int lda, ka;
    if (k0 < ksplit) { Abase = A0; lda = lda0; ka = k0; }
    else             { Abase = A1; lda = lda1; ka = k0 - ksplit; }
#pragma unroll
    for (int c = 0; c < 2; ++c) {
      int ch = wave + c * 4;  // chunk 0..7 (16 rows x 32 k each, 1024B)
      int r = ch * 16 + srow;
      gload_lds16(Abase + (size_t)(brow + r) * lda + ka + scol, As + ch * 512);
      gload_lds16(Bt + (size_t)(bcol + r) * ldb + k0 + scol, Bs + ch * 512);
    }
    __syncthreads();
    bf16x8 af[4], bfr[4];
#pragma unroll
    for (int m = 0; m < 4; ++m)
      af[m] = *(const bf16x8*)(As + (wr * 64 + m * 16 + lrow) * 32 + kb);
#pragma unroll
    for (int n = 0; n < 4; ++n)
      bfr[n] = *(const bf16x8*)(Bs + (wc * 64 + n * 16 + lrow) * 32 + kb);
#pragma unroll
    for (int m = 0; m < 4; ++m)
#pragma unroll
      for (int n = 0; n < 4; ++n)
        acc[m][n] = __builtin_amdgcn_mfma_f32_16x16x32_bf16(af[m], bfr[n], acc[m][n], 0, 0, 0);
    __syncthreads();
  }

  // epilogue: C/D layout col=lane&15, row=(lane>>4)*4+reg  [verified m89/m91]
#pragma unroll
  for (int m = 0; m < 4; ++m) {
#pragma unroll
    for (int n = 0; n < 4; ++n) {
      int col = bcol + wc * 64 + n * 16 + lrow;
#pragma unroll
      for (int q = 0; q < 4; ++q) {
        int row = brow + wr * 64 + m * 16 + (lane >> 4) * 4 + q;
        float v = acc[m][n][q];
        if (EPI == 0) {
          if (col < UNITS) {
            zbuf[(size_t)row * UNITS + col] = v + bias_a[col] + bias_b[col];
          } else {
            int j = col - UNITS;
            float r = v + bias_c[j] + bias_d[j];
            rxbuf[(size_t)row * UNITS + j] = (bf16)(r * xin[(size_t)row * UNITS + j]);
          }
        } else {
          float a = v + bias_a[col] + bias_b[col];
          float z = zbuf[(size_t)row * UNITS + col];
          float xv = xin[(size_t)row * UNITS + col];
          outbuf[(size_t)row * UNITS + col] = (1.f - z) * xv + z * tanhf(a);
        }
      }
    }
  }
}

extern "C" void kernel_launch(void* const* d_in, const int* in_sizes, int n_in,
                              void* d_out, int out_size, void* d_ws, size_t ws_size,
                              hipStream_t stream) {
  const float* x   = (const float*)d_in[0];
  const float* y   = (const float*)d_in[1];
  const float* Wz  = (const float*)d_in[2];
  const float* bz  = (const float*)d_in[3];
  const float* Uz  = (const float*)d_in[4];
  const float* buz = (const float*)d_in[5];
  const float* Wr  = (const float*)d_in[6];
  const float* br  = (const float*)d_in[7];
  const float* Ur  = (const float*)d_in[8];
  const float* bur = (const float*)d_in[9];
  const float* Wg  = (const float*)d_in[10];
  const float* bg  = (const float*)d_in[11];
  const float* Ug  = (const float*)d_in[12];
  const float* bug = (const float*)d_in[13];
  float* out = (float*)d_out;

  char* w = (char*)d_ws;
  bf16* Ybf = (bf16*)w;  w += (size_t)NROWS * UNITS * 2;     // 32 MiB
  bf16* Xbf = (bf16*)w;  w += (size_t)NROWS * UNITS * 2;     // 32 MiB
  bf16* RX  = (bf16*)w;  w += (size_t)NROWS * UNITS * 2;     // 32 MiB
  bf16* Bzr = (bf16*)w;  w += (size_t)4096 * 4096 * 2;       // 32 MiB  [4096 cols][K=4096]
  bf16* Bgt = (bf16*)w;  w += (size_t)2048 * 4096 * 2;       // 16 MiB  [2048 cols][K=4096]
  float* Zb = (float*)w; w += (size_t)NROWS * UNITS * 4;     // 64 MiB

  pack_xy_kernel<<<2048, 256, 0, stream>>>(x, y, Xbf, Ybf);

  dim3 tg(64, 64);
  // Bzr rows 0..2047 (z cols): [Wz ; Uz], rows 2048..4095 (r cols): [Wr ; Ur]
  transpose_cvt_kernel<<<tg, 256, 0, stream>>>(Wz, Bzr, 4096, 0);
  transpose_cvt_kernel<<<tg, 256, 0, stream>>>(Uz, Bzr, 4096, 2048);
  transpose_cvt_kernel<<<tg, 256, 0, stream>>>(Wr, Bzr + (size_t)2048 * 4096, 4096, 0);
  transpose_cvt_kernel<<<tg, 256, 0, stream>>>(Ur, Bzr + (size_t)2048 * 4096, 4096, 2048);
  // Bg: [Wg ; Ug]
  transpose_cvt_kernel<<<tg, 256, 0, stream>>>(Wg, Bgt, 4096, 0);
  transpose_cvt_kernel<<<tg, 256, 0, stream>>>(Ug, Bgt, 4096, 2048);

  // GEMM1: [8192 x 4096] = [Y|X] @ Bzr^T  -> z (fp32), rx (bf16)
  dim3 g1(4096 / 128, NROWS / 128);
  gemm_bt<0><<<g1, 256, 0, stream>>>(Ybf, Xbf, Bzr, UNITS, UNITS, 4096, UNITS, 4096,
                                     bz, buz, br, bur, x, Zb, RX, nullptr);
  // GEMM2: [8192 x 2048] = [Y|RX] @ Bg^T -> out
  dim3 g2(2048 / 128, NROWS / 128);
  gemm_bt<1><<<g2, 256, 0, stream>>>(Ybf, RX, Bgt, UNITS, UNITS, 4096, UNITS, 4096,
                                     bg, bug, nullptr, nullptr, x, Zb, nullptr, out);
}

// Round 2
// 530.726 us; speedup vs baseline: 1.5180x; 1.5180x over previous
//
#include <hip/hip_runtime.h>
#include <hip/hip_bf16.h>
#include <cstdint>
#include <cmath>

typedef __bf16 bf16;
typedef __bf16 bf16x8 __attribute__((ext_vector_type(8)));
typedef __bf16 bf16x4 __attribute__((ext_vector_type(4)));
typedef float f32x4 __attribute__((ext_vector_type(4)));

#define NROWS 8192
#define UNITS 2048
#define BM 256
#define BN 256
#define BK 64
#define NT 64      // K = 4096 / BK
#define NSPLIT 32  // tile index where A switches from A0 to A1

__device__ __forceinline__ void gload_lds16(const bf16* g, const bf16* lds) {
  __builtin_amdgcn_global_load_lds(
      (const __attribute__((address_space(1))) uint32_t*)(uintptr_t)g,
      (__attribute__((address_space(3))) uint32_t*)(uint32_t)(uintptr_t)lds,
      16, 0, 0);
}

#define PH_BAR do { asm volatile("" ::: "memory"); __builtin_amdgcn_s_barrier(); asm volatile("" ::: "memory"); } while (0)
#define WAITV4 asm volatile("s_waitcnt vmcnt(4)" ::: "memory")
#define WAITV0 asm volatile("s_waitcnt vmcnt(0)" ::: "memory")

// ---- pack x,y fp32 -> bf16
__global__ void pack_xy_kernel(const float* __restrict__ x, const float* __restrict__ y,
                               bf16* __restrict__ xb, bf16* __restrict__ yb) {
  size_t n4 = (size_t)NROWS * UNITS / 4;
  size_t stride = (size_t)gridDim.x * blockDim.x;
  for (size_t i = (size_t)blockIdx.x * blockDim.x + threadIdx.x; i < n4; i += stride) {
    float4 vx = ((const float4*)x)[i];
    float4 vy = ((const float4*)y)[i];
    bf16x4 ox = {(bf16)vx.x, (bf16)vx.y, (bf16)vx.z, (bf16)vx.w};
    bf16x4 oy = {(bf16)vy.x, (bf16)vy.y, (bf16)vy.z, (bf16)vy.w};
    ((bf16x4*)xb)[i] = ox;
    ((bf16x4*)yb)[i] = oy;
  }
}

// ---- tiled transpose + convert: dst[j*ldd + koff + k] = (bf16) src[k*2048 + j]
__global__ void transpose_cvt_kernel(const float* __restrict__ src, bf16* __restrict__ dst,
                                     int ldd, int koff) {
  __shared__ float t[32][33];
  int j0 = blockIdx.x * 32, k0 = blockIdx.y * 32;
  int tx = threadIdx.x & 31, ty = threadIdx.x >> 5;
#pragma unroll
  for (int i = 0; i < 32; i += 8)
    t[ty + i][tx] = src[(size_t)(k0 + ty + i) * UNITS + j0 + tx];
  __syncthreads();
#pragma unroll
  for (int i = 0; i < 32; i += 8)
    dst[(size_t)(j0 + ty + i) * ldd + koff + k0 + tx] = (bf16)t[tx][ty + i];
}

// ================= 256x256 8-phase GEMM, C = A @ Bt^T ====================
// A = [A0 | A1] along K (each lda=2048), Bt row-major [Ncols][4096].
// EPI 0: cols<2048 -> z=acc+ba+bb (fp32); cols>=2048 -> rx=(acc+bc+bd)*x (bf16)
// EPI 1: out = (1-z)*x + z*tanh(acc+ba+bb)
template <int EPI>
__global__ __launch_bounds__(512)
void gemm256(const bf16* __restrict__ A0, const bf16* __restrict__ A1,
             const bf16* __restrict__ Bt,
             const float* __restrict__ bias_a, const float* __restrict__ bias_b,
             const float* __restrict__ bias_c, const float* __restrict__ bias_d,
             const float* __restrict__ xin, float* __restrict__ zbuf,
             bf16* __restrict__ rxbuf, float* __restrict__ outbuf) {
  __shared__ bf16 LDS[2][32768];  // per buf: A[0,16384) B[16384,32768); 128 KiB total
  const int tid = threadIdx.x;
  const int wv = tid >> 6, lane = tid & 63;
  const int wr = wv >> 2, wc = wv & 3;

  // XCD-aware swizzle (nwg % 8 == 0 for both GEMMs); by varies fastest -> B-panel L2 reuse
  const int nwg = gridDim.x;
  const int bs = ((int)blockIdx.x & 7) * (nwg >> 3) + ((int)blockIdx.x >> 3);
  const int by = bs & 31;         // NROWS/BM = 32
  const int bx = bs >> 5;
  const int brow = by * BM;
  const int bcol = bx * BN;

  // ---- staging source offsets (pre-inverse-swizzled; LDS dest stays linear) ----
  // linear dest elem e = c*4096 + tid*8 within a 128x64 half; subtile = 16 rows x 32 k (512 el)
  // swizzle (involution): k' = k ^ ((r&6)<<2)
  int offA[2][2], offB[2][2];
#pragma unroll
  for (int c = 0; c < 2; ++c) {
    int e = c * 4096 + tid * 8;
    int s = e >> 9, w = e & 511;
    int r = w >> 5;
    int kk = (w & 31) ^ ((r & 6) << 2);
    int grow = (s >> 1) * 16 + r;
    int gk = (s & 1) * 32 + kk;
    offA[0][c] = (brow + grow) * 2048 + gk;
    offA[1][c] = offA[0][c] + 128 * 2048;
    offB[0][c] = (bcol + grow) * 4096 + gk;
    offB[1][c] = offB[0][c] + 128 * 4096;
  }

  // ---- fragment read offsets (swizzled) ----
  const int lr = lane & 15;
  const int kread = ((lane >> 4) * 8) ^ ((lr & 6) << 2);
  const int abase = wr * 8192 + lr * 32 + kread;                        // + (m*2+kh)*512
  const int bbase = 16384 + (wc >> 1) * 8192 + (wc & 1) * 4096 + lr * 32 + kread;  // + (n*2+kh)*512

#define ST_A(TI, H, BUFP)                                                        \
  if ((TI) < NT) {                                                               \
    const bf16* _s = ((TI) < NSPLIT) ? A0 + (size_t)(TI)*BK                      \
                                     : A1 + (size_t)((TI) - NSPLIT) * BK;        \
    gload_lds16(_s + offA[H][0], (BUFP) + (H)*8192 + wv * 512);                  \
    gload_lds16(_s + offA[H][1], (BUFP) + (H)*8192 + 4096 + wv * 512);           \
  }
#define ST_B(TI, H, BUFP)                                                        \
  if ((TI) < NT) {                                                               \
    const bf16* _s = Bt + (size_t)(TI)*BK;                                       \
    gload_lds16(_s + offB[H][0], (BUFP) + 16384 + (H)*8192 + wv * 512);          \
    gload_lds16(_s + offB[H][1], (BUFP) + 16384 + (H)*8192 + 4096 + wv * 512);   \
  }

  f32x4 acc[8][4];
#pragma unroll
  for (int m = 0; m < 8; ++m)
#pragma unroll
    for (int n = 0; n < 4; ++n) {
      f32x4 zz = {0.f, 0.f, 0.f, 0.f};
      acc[m][n] = zz;
    }

  // ---- prologue: tile0 (all 4 halves), then B0(1), A0(1); confirm tile0 ----
  {
    bf16* L0 = &LDS[0][0];
    bf16* L1 = &LDS[1][0];
    ST_A(0, 0, L0); ST_A(0, 1, L0); ST_B(0, 0, L0); ST_B(0, 1, L0);
    ST_B(1, 0, L1); ST_A(1, 0, L1);
    WAITV4;
    PH_BAR;
  }

#define MFMA_Q(AARR, BARR, MOFF, NOFF)                                           \
  __builtin_amdgcn_s_setprio(1);                                                 \
  _Pragma("unroll") for (int kh = 0; kh < 2; ++kh)                               \
  _Pragma("unroll") for (int m = 0; m < 4; ++m)                                  \
  _Pragma("unroll") for (int n = 0; n < 2; ++n)                                  \
      acc[m + MOFF][n + NOFF] = __builtin_amdgcn_mfma_f32_16x16x32_bf16(         \
          AARR[m][kh], BARR[n][kh], acc[m + MOFF][n + NOFF], 0, 0, 0);           \
  __builtin_amdgcn_s_setprio(0);

#define TILE(T, CUR, NXT)                                                        \
  {                                                                              \
    const bf16* Lc = &LDS[CUR][0];                                               \
    bf16* Lcw = &LDS[CUR][0];                                                    \
    bf16* Ln = &LDS[NXT][0];                                                     \
    bf16x8 a0[4][2], a1[4][2], b0[2][2], b1[2][2];                               \
    /* P1: read a0 (Mh0) + b0 (Nh0); stage A1(t+1)->NXT */                       \
    _Pragma("unroll") for (int m = 0; m < 4; ++m)                                \
    _Pragma("unroll") for (int kh = 0; kh < 2; ++kh)                             \
        a0[m][kh] = *(const bf16x8*)(Lc + abase + (m * 2 + kh) * 512);           \
    _Pragma("unroll") for (int n = 0; n < 2; ++n)                                \
    _Pragma("unroll") for (int kh = 0; kh < 2; ++kh)                             \
        b0[n][kh] = *(const bf16x8*)(Lc + bbase + (n * 2 + kh) * 512);           \
    ST_A((T) + 1, 1, Ln);                                                        \
    PH_BAR;                                                                      \
    MFMA_Q(a0, b0, 0, 0);                                                        \
    PH_BAR;                                                                      \
    /* P2: read b1 (Nh1); stage B1(t+1)->NXT */                                  \
    _Pragma("unroll") for (int n = 0; n < 2; ++n)                                \
    _Pragma("unroll") for (int kh = 0; kh < 2; ++kh)                             \
        b1[n][kh] = *(const bf16x8*)(Lc + bbase + ((n + 2) * 2 + kh) * 512);     \
    ST_B((T) + 1, 1, Ln);                                                        \
    PH_BAR;                                                                      \
    MFMA_Q(a0, b1, 0, 2);                                                        \
    PH_BAR;                                                                      \
    /* P3: read a1 (Mh1); stage B0(t+2)->CUR (B reads done at P2) */             \
    _Pragma("unroll") for (int m = 0; m < 4; ++m)                                \
    _Pragma("unroll") for (int kh = 0; kh < 2; ++kh)                             \
        a1[m][kh] = *(const bf16x8*)(Lc + abase + ((m + 4) * 2 + kh) * 512);     \
    ST_B((T) + 2, 0, Lcw);                                                       \
    PH_BAR;                                                                      \
    MFMA_Q(a1, b0, 4, 0);                                                        \
    PH_BAR;                                                                      \
    /* P4: stage A0(t+2)->CUR (A reads done at P3); counted vmcnt */             \
    ST_A((T) + 2, 0, Lcw);                                                       \
    PH_BAR;                                                                      \
    MFMA_Q(a1, b1, 4, 2);                                                        \
    if ((T) < NT - 2) { WAITV4; } else { WAITV0; }                               \
    PH_BAR;                                                                      \
  }

#pragma unroll 1
  for (int t = 0; t < NT; t += 2) {
    TILE(t, 0, 1);
    TILE(t + 1, 1, 0);
  }

  // ---- epilogue: C/D layout col=lane&15, row=(lane>>4)*4+q ----
  const int lq = (lane >> 4) << 2;
  const int lc = lane & 15;
  const int rowb = brow + wr * 128;
  const int colb = bcol + wc * 64;
  if constexpr (EPI == 0) {
    if (bcol < UNITS) {
#pragma unroll
      for (int m = 0; m < 8; ++m)
#pragma unroll
        for (int n = 0; n < 4; ++n) {
          int col = colb + n * 16 + lc;
          float ba = bias_a[col] + bias_b[col];
#pragma unroll
          for (int q = 0; q < 4; ++q) {
            int row = rowb + m * 16 + lq + q;
            zbuf[(size_t)row * UNITS + col] = acc[m][n][q] + ba;
          }
        }
    } else {
#pragma unroll
      for (int m = 0; m < 8; ++m)
#pragma unroll
        for (int n = 0; n < 4; ++n) {
          int col = colb - UNITS + n * 16 + lc;
          float bc = bias_c[col] + bias_d[col];
#pragma unroll
          for (int q = 0; q < 4; ++q) {
            int row = rowb + m * 16 + lq + q;
            size_t idx = (size_t)row * UNITS + col;
            float r = acc[m][n][q] + bc;
            rxbuf[idx] = (bf16)(r * xin[idx]);
          }
        }
    }
  } else {
#pragma unroll
    for (int m = 0; m < 8; ++m)
#pragma unroll
      for (int n = 0; n < 4; ++n) {
        int col = colb + n * 16 + lc;
        float bg_ = bias_a[col] + bias_b[col];
#pragma unroll
        for (int q = 0; q < 4; ++q) {
          int row = rowb + m * 16 + lq + q;
          size_t idx = (size_t)row * UNITS + col;
          float h = tanhf(acc[m][n][q] + bg_);
          float zv = zbuf[idx];
          float xv = xin[idx];
          outbuf[idx] = (1.f - zv) * xv + zv * h;
        }
      }
  }
#undef ST_A
#undef ST_B
#undef MFMA_Q
#undef TILE
}

extern "C" void kernel_launch(void* const* d_in, const int* in_sizes, int n_in,
                              void* d_out, int out_size, void* d_ws, size_t ws_size,
                              hipStream_t stream) {
  const float* x   = (const float*)d_in[0];
  const float* y   = (const float*)d_in[1];
  const float* Wz  = (const float*)d_in[2];
  const float* bz  = (const float*)d_in[3];
  const float* Uz  = (const float*)d_in[4];
  const float* buz = (const float*)d_in[5];
  const float* Wr  = (const float*)d_in[6];
  const float* br  = (const float*)d_in[7];
  const float* Ur  = (const float*)d_in[8];
  const float* bur = (const float*)d_in[9];
  const float* Wg  = (const float*)d_in[10];
  const float* bg  = (const float*)d_in[11];
  const float* Ug  = (const float*)d_in[12];
  const float* bug = (const float*)d_in[13];
  float* out = (float*)d_out;

  char* w = (char*)d_ws;
  bf16* Ybf = (bf16*)w;  w += (size_t)NROWS * UNITS * 2;  // 32 MiB
  bf16* Xbf = (bf16*)w;  w += (size_t)NROWS * UNITS * 2;  // 32 MiB
  bf16* RX  = (bf16*)w;  w += (size_t)NROWS * UNITS * 2;  // 32 MiB
  bf16* Bzr = (bf16*)w;  w += (size_t)4096 * 4096 * 2;    // 32 MiB [4096 cols][K=4096]
  bf16* Bgt = (bf16*)w;  w += (size_t)2048 * 4096 * 2;    // 16 MiB [2048 cols][K=4096]
  float* Zb = (float*)w; w += (size_t)NROWS * UNITS * 4;  // 64 MiB

  pack_xy_kernel<<<2048, 256, 0, stream>>>(x, y, Xbf, Ybf);

  dim3 tg(64, 64);
  transpose_cvt_kernel<<<tg, 256, 0, stream>>>(Wz, Bzr, 4096, 0);
  transpose_cvt_kernel<<<tg, 256, 0, stream>>>(Uz, Bzr, 4096, 2048);
  transpose_cvt_kernel<<<tg, 256, 0, stream>>>(Wr, Bzr + (size_t)2048 * 4096, 4096, 0);
  transpose_cvt_kernel<<<tg, 256, 0, stream>>>(Ur, Bzr + (size_t)2048 * 4096, 4096, 2048);
  transpose_cvt_kernel<<<tg, 256, 0, stream>>>(Wg, Bgt, 4096, 0);
  transpose_cvt_kernel<<<tg, 256, 0, stream>>>(Ug, Bgt, 4096, 2048);

  // GEMM1: [8192 x 4096] = [Y|X] @ Bzr^T -> z (fp32), rx (bf16)
  gemm256<0><<<512, 512, 0, stream>>>(Ybf, Xbf, Bzr, bz, buz, br, bur, x, Zb, RX, nullptr);
  // GEMM2: [8192 x 2048] = [Y|RX] @ Bg^T -> out
  gemm256<1><<<256, 512, 0, stream>>>(Ybf, RX, Bgt, bg, bug, nullptr, nullptr, x, Zb, nullptr, out);
}